// Round 1
// baseline (42.840 us; speedup 1.0000x reference)
//
#include <hip/hip_runtime.h>

#define KP 137
#define SS 512
#define BB 128
#define DD (2 * KP)        // 274
#define NROWS (BB * SS)    // 65536
#define NBLK 8192
#define THREADS 128

__global__ __launch_bounds__(THREADS) void t2p_main(
    const float* __restrict__ pred,      // [B,S,2K]
    const float* __restrict__ tgt,       // [B,2,S,K]
    const int*   __restrict__ tlen,      // [B]
    float2* __restrict__ partials)       // [NBLK]
{
    __shared__ float2 e_sh[KP + 1];
    __shared__ float2 wsum[THREADS / 64];

    const int t = threadIdx.x;
    float pose_acc = 0.f, bone_acc = 0.f;

    for (int row = blockIdx.x; row < NROWS; row += NBLK) {
        const int b = row >> 9;          // S = 512
        const int s = row & (SS - 1);
        const int len = tlen[b];
        const bool vbone = (s < len);
        if (!vbone) continue;            // block-uniform: s,b uniform per iteration
        const bool vpose = (s < SS - 1) && (s < len - 1);

        const float2* __restrict__ prow =
            (const float2*)(pred + (size_t)row * DD);
        const float* __restrict__ tx =
            tgt + (size_t)b * 2 * SS * KP + (size_t)s * KP;   // c=0 plane, row s
        const float* __restrict__ ty = tx + (size_t)SS * KP;  // c=1 plane, row s

        for (int k = t; k < KP; k += THREADS) {
            float2 p = prow[k];                   // (x_k, y_k) of predicted
            float ex = p.x - tx[k];
            float ey = p.y - ty[k];
            e_sh[k] = make_float2(ex, ey);
            if (vpose) {
                // tp at row s+1 is +K floats within each plane
                pose_acc += fabsf(p.x - tx[k + KP]) + fabsf(p.y - ty[k + KP]);
            }
        }
        __syncthreads();
        for (int k = t; k < KP - 1; k += THREADS) {
            float2 e0 = e_sh[k];
            float2 e1 = e_sh[k + 1];
            float dx = e1.x - e0.x;
            float dy = e1.y - e0.y;
            bone_acc += dx * dx + dy * dy;
        }
        __syncthreads();
    }

    // block reduce (2 waves)
    for (int off = 32; off > 0; off >>= 1) {
        pose_acc += __shfl_down(pose_acc, off, 64);
        bone_acc += __shfl_down(bone_acc, off, 64);
    }
    const int wid = t >> 6;
    if ((t & 63) == 0) wsum[wid] = make_float2(pose_acc, bone_acc);
    __syncthreads();
    if (t == 0) {
        float2 a = wsum[0], c = wsum[1];
        partials[blockIdx.x] = make_float2(a.x + c.x, a.y + c.y);
    }
}

__global__ __launch_bounds__(256) void t2p_final(
    const float2* __restrict__ partials,
    const int* __restrict__ tlen,
    float* __restrict__ out)
{
    const int t = threadIdx.x;
    float ps = 0.f, bs = 0.f;
    for (int i = t; i < NBLK; i += 256) {
        float2 v = partials[i];
        ps += v.x; bs += v.y;
    }
    float pc = 0.f, mc = 0.f;
    if (t < BB) {
        int len = tlen[t];
        pc = (float)(len - 1);   // sum(pose_mask) contribution
        mc = (float)len;         // sum(mask) contribution
    }
    for (int off = 32; off > 0; off >>= 1) {
        ps += __shfl_down(ps, off, 64);
        bs += __shfl_down(bs, off, 64);
        pc += __shfl_down(pc, off, 64);
        mc += __shfl_down(mc, off, 64);
    }
    __shared__ float4 wsum[4];
    const int wid = t >> 6;
    if ((t & 63) == 0) wsum[wid] = make_float4(ps, bs, pc, mc);
    __syncthreads();
    if (t == 0) {
        float4 a = wsum[0];
        for (int w = 1; w < 4; ++w) {
            a.x += wsum[w].x; a.y += wsum[w].y;
            a.z += wsum[w].z; a.w += wsum[w].w;
        }
        float pose_loss = a.x / (274.f * a.z);
        float bone_loss = (a.y * 0.5f) / ((136.f + 1e-8f) * a.w);
        out[0] = pose_loss + 0.1f * bone_loss;  // POSE_W=1.0, BONE_W=0.1
        out[1] = pose_loss;
        out[2] = bone_loss;
    }
}

extern "C" void kernel_launch(void* const* d_in, const int* in_sizes, int n_in,
                              void* d_out, int out_size, void* d_ws, size_t ws_size,
                              hipStream_t stream) {
    const float* pred = (const float*)d_in[0];   // predicted_poses [128,512,274]
    const float* tgt  = (const float*)d_in[1];   // target_poses   [128,2,512,137]
    const int*   tlen = (const int*)d_in[2];     // target_length  [128]
    float* out = (float*)d_out;                  // (total, pose, bone)
    float2* partials = (float2*)d_ws;            // 8192 * 8 B = 64 KB

    t2p_main<<<NBLK, THREADS, 0, stream>>>(pred, tgt, tlen, partials);
    t2p_final<<<1, 256, 0, stream>>>(partials, tlen, out);
}

// Round 2
// 30.758 us; speedup vs baseline: 1.3928x; 1.3928x over previous
//
#include <hip/hip_runtime.h>

#define KP 137
#define SS 512
#define BB 128
#define TS 16
#define NTILE (BB * (SS / TS))   // 4096
#define THREADS 256

// LDS layout (float offsets) — regions are flat unpadded copies (global_load_lds
// writes linearly: wave-uniform base + lane*16, so no padding allowed).
#define PRED_F 0
#define PRED_N (TS * 2 * KP)            // 4384 floats = 17536 B
#define TX_F   PRED_N
#define PLANE_CAP 2336                  // >= 583*4 floats, keeps 16B alignment
#define TY_F   (TX_F + PLANE_CAP)
#define LDS_N  (TY_F + PLANE_CAP)       // 9056 floats = 36224 B -> 4 blocks/CU

__device__ __forceinline__ void gload_lds16(const float* g, float* l) {
    __builtin_amdgcn_global_load_lds(
        (const __attribute__((address_space(1))) void*)g,
        (__attribute__((address_space(3))) void*)l, 16, 0, 0);
}

// Copy nbytes (16B-aligned start; nbytes multiple of 16) global -> LDS.
// Chunks of 1 KB per wave-call; 4 waves round-robin. Inactive lanes masked.
__device__ __forceinline__ void stage(const float* g, float* l, int nbytes, int t) {
    const int lane = t & 63;
    const int wv = t >> 6;
    for (int c = wv; c * 1024 < nbytes; c += 4) {
        const int off = c * 1024 + lane * 16;
        if (off < nbytes)
            gload_lds16((const float*)((const char*)g + off),
                        (float*)((char*)l + c * 1024));
    }
}

__global__ __launch_bounds__(THREADS) void t2p_main(
    const float* __restrict__ pred,      // [B,S,2K]
    const float* __restrict__ tgt,       // [B,2,S,K]
    const int*   __restrict__ tlen,      // [B]
    float2* __restrict__ partials)       // [NTILE]
{
    __shared__ float lds[LDS_N];
    __shared__ float2 wsum[THREADS / 64];

    const int t = threadIdx.x;
    const int bid = blockIdx.x;
    const int b = bid >> 5;              // 32 tiles per batch row
    const int s0 = (bid & 31) * TS;
    const int len = tlen[b];

    if (s0 >= len) {                     // whole tile masked out
        if (t == 0) partials[bid] = make_float2(0.f, 0.f);
        return;
    }

    // ---- stage tile: pred rows s0..s0+15, target rows s0..s0+16 (clamped) ----
    const int rows17 = (s0 + 17 <= SS) ? 17 : (SS - s0);      // 17, or 16 for last tile
    const int nb_t   = rows17 * KP * 4;                        // plane bytes
    const int nb_tr  = (nb_t + 15) & ~15;                      // round up (<=12B over-read, in-bounds)

    stage(pred + (size_t)(b * SS + s0) * (2 * KP), &lds[PRED_F], TS * 2 * KP * 4, t);
    stage(tgt + ((size_t)(b * 2 + 0) * SS + s0) * KP, &lds[TX_F], nb_tr, t);
    stage(tgt + ((size_t)(b * 2 + 1) * SS + s0) * KP, &lds[TY_F], nb_tr, t);
    __syncthreads();   // compiler emits vmcnt(0) drain before barrier -> LDS valid

    // ---- compute: thread = (row r, k-segment sub), 9 k's per segment ----
    float pose = 0.f, bone = 0.f;
    const int r   = t >> 4;              // 0..15
    const int sub = t & 15;              // 0..15
    const int s   = s0 + r;
    if (s < len) {
        const float* pr  = &lds[PRED_F + r * 2 * KP];
        const float* tx0 = &lds[TX_F + r * KP];
        const float* ty0 = &lds[TY_F + r * KP];
        const int k0 = sub * 9;

        if (s < len - 1) {               // pose term uses target row s+1
            const float* tx1 = tx0 + KP;
            const float* ty1 = ty0 + KP;
            #pragma unroll
            for (int j = 0; j < 9; ++j) {
                const int k = k0 + j;
                if (k < KP)
                    pose += fabsf(pr[2 * k]     - tx1[k]) +
                            fabsf(pr[2 * k + 1] - ty1[k]);
            }
        }
        #pragma unroll
        for (int j = 0; j < 9; ++j) {    // bone pairs (k,k+1), k < 136
            const int k = k0 + j;
            if (k < KP - 1) {
                float e0x = pr[2 * k]     - tx0[k];
                float e0y = pr[2 * k + 1] - ty0[k];
                float e1x = pr[2 * k + 2] - tx0[k + 1];
                float e1y = pr[2 * k + 3] - ty0[k + 1];
                float dx = e1x - e0x, dy = e1y - e0y;
                bone += dx * dx + dy * dy;
            }
        }
    }

    // ---- block reduce (4 waves) ----
    for (int off = 32; off > 0; off >>= 1) {
        pose += __shfl_down(pose, off, 64);
        bone += __shfl_down(bone, off, 64);
    }
    if ((t & 63) == 0) wsum[t >> 6] = make_float2(pose, bone);
    __syncthreads();
    if (t == 0) {
        float px = 0.f, bx = 0.f;
        for (int w = 0; w < THREADS / 64; ++w) { px += wsum[w].x; bx += wsum[w].y; }
        partials[bid] = make_float2(px, bx);
    }
}

__global__ __launch_bounds__(256) void t2p_final(
    const float2* __restrict__ partials,
    const int* __restrict__ tlen,
    float* __restrict__ out)
{
    const int t = threadIdx.x;
    float ps = 0.f, bs = 0.f;
    for (int i = t; i < NTILE; i += 256) {
        float2 v = partials[i];
        ps += v.x; bs += v.y;
    }
    float pc = 0.f, mc = 0.f;
    if (t < BB) {
        int len = tlen[t];
        pc = (float)(len - 1);   // sum(pose_mask)
        mc = (float)len;         // sum(mask)
    }
    for (int off = 32; off > 0; off >>= 1) {
        ps += __shfl_down(ps, off, 64);
        bs += __shfl_down(bs, off, 64);
        pc += __shfl_down(pc, off, 64);
        mc += __shfl_down(mc, off, 64);
    }
    __shared__ float4 wsum[4];
    if ((t & 63) == 0) wsum[t >> 6] = make_float4(ps, bs, pc, mc);
    __syncthreads();
    if (t == 0) {
        float4 a = wsum[0];
        for (int w = 1; w < 4; ++w) {
            a.x += wsum[w].x; a.y += wsum[w].y;
            a.z += wsum[w].z; a.w += wsum[w].w;
        }
        float pose_loss = a.x / (274.f * a.z);
        float bone_loss = (a.y * 0.5f) / ((136.f + 1e-8f) * a.w);
        out[0] = pose_loss + 0.1f * bone_loss;   // POSE_W=1, BONE_W=0.1
        out[1] = pose_loss;
        out[2] = bone_loss;
    }
}

extern "C" void kernel_launch(void* const* d_in, const int* in_sizes, int n_in,
                              void* d_out, int out_size, void* d_ws, size_t ws_size,
                              hipStream_t stream) {
    const float* pred = (const float*)d_in[0];   // [128,512,274] f32
    const float* tgt  = (const float*)d_in[1];   // [128,2,512,137] f32
    const int*   tlen = (const int*)d_in[2];     // [128] i32
    float* out = (float*)d_out;
    float2* partials = (float2*)d_ws;            // 4096 * 8 B = 32 KB

    t2p_main<<<NTILE, THREADS, 0, stream>>>(pred, tgt, tlen, partials);
    t2p_final<<<1, 256, 0, stream>>>(partials, tlen, out);
}

// Round 3
// 29.273 us; speedup vs baseline: 1.4635x; 1.0507x over previous
//
#include <hip/hip_runtime.h>

#define KP 137
#define SS 512
#define BB 128

#define THREADS 256
#define NBLK 1024                 // 4096 waves x 16 rows = 65536 rows
#define CH 4                      // rows per chunk
#define NCHMAX 4                  // chunks per wave-tile (16 rows)

// Per-wave LDS slice (floats): pred 4 rows (1096) + 2 planes (688 each, 2752 B cap)
#define PRED_F 1096
#define PLANE_F 688
#define SLICE_F (PRED_F + 2 * PLANE_F)          // 2472 floats = 9888 B
#define WAVE_F (2 * SLICE_F)                    // double buffer: 19776 B/wave
#define LDS_F (4 * WAVE_F)                      // 79104 B/block -> 2 blocks/CU

__device__ __forceinline__ void gl16(const float* g, float* l) {
    __builtin_amdgcn_global_load_lds(
        (const __attribute__((address_space(1))) void*)g,
        (__attribute__((address_space(3))) void*)l, 16, 0, 0);
}

// Stage one chunk: EXACTLY 11 vmem instructions per wave (every inst has >=1
// active lane), so vmcnt bookkeeping is compile-time exact.
__device__ __forceinline__ void stage_chunk(
    const float* pg, const float* xg, const float* yg,
    float* lp, float* lx, float* ly, int lane, int tail_lanes)
{
    const float* p4 = pg + lane * 4;
    gl16(p4,        lp);            // 1 KB each: HW writes base + lane*16
    gl16(p4 + 256,  lp + 256);
    gl16(p4 + 512,  lp + 512);
    gl16(p4 + 768,  lp + 768);
    if (lane < 18) gl16(p4 + 1024, lp + 1024);       // 288 B tail
    const float* x4 = xg + lane * 4;
    gl16(x4,        lx);
    gl16(x4 + 256,  lx + 256);
    if (lane < tail_lanes) gl16(x4 + 512, lx + 512); // 704 B or 144 B tail
    const float* y4 = yg + lane * 4;
    gl16(y4,        ly);
    gl16(y4 + 256,  ly + 256);
    if (lane < tail_lanes) gl16(y4 + 512, ly + 512);
}

__device__ __forceinline__ void compute_chunk(
    const float* bp, int s0, int len, int lane, float& pose, float& bone)
{
    const int r   = lane >> 4;        // 0..3  (row within chunk)
    const int sub = lane & 15;        // 0..15 (k-segment)
    const int s   = s0 + r;
    if (s >= len) return;
    const bool dopose = (s < len - 1);           // len<=512 => also s<511

    const float* pr  = bp + r * (2 * KP);
    const float* tx0 = bp + PRED_F + r * KP;
    const float* ty0 = bp + PRED_F + PLANE_F + r * KP;
    const float* tx1 = tx0 + KP;
    const float* ty1 = ty0 + KP;

    const int k0 = sub * 9;           // 16*9=144 covers 137 kps / 136 pairs
    float px = pr[2 * k0], py = pr[2 * k0 + 1];
    float ex0 = px - tx0[k0], ey0 = py - ty0[k0];
    if (dopose) pose += fabsf(px - tx1[k0]) + fabsf(py - ty1[k0]);

    #pragma unroll
    for (int j = 1; j <= 9; ++j) {
        const int k = k0 + j;
        if (k <= KP - 1) {
            float qx = pr[2 * k], qy = pr[2 * k + 1];
            float ex1 = qx - tx0[k], ey1 = qy - ty0[k];
            float dx = ex1 - ex0, dy = ey1 - ey0;
            bone += dx * dx + dy * dy;            // pair (k-1, k), k-1 <= 135
            if (dopose && j < 9) pose += fabsf(qx - tx1[k]) + fabsf(qy - ty1[k]);
            ex0 = ex1; ey0 = ey1;
        }
    }
}

__global__ __launch_bounds__(THREADS) void t2p_main(
    const float* __restrict__ pred,      // [B,S,2K]
    const float* __restrict__ tgt,       // [B,2,S,K]
    const int*   __restrict__ tlen,      // [B]
    float2* __restrict__ partials)       // [NBLK]
{
    __shared__ float lds[LDS_F];
    __shared__ float2 wsum[4];

    const int t    = threadIdx.x;
    const int lane = t & 63;
    const int wid  = t >> 6;
    const int w    = blockIdx.x * 4 + wid;       // global wave id, 0..4095
    const int b    = w >> 5;                     // 32 tiles per batch row
    const int sbase = (w & 31) * 16;
    const int len  = tlen[b];

    float pose = 0.f, bone = 0.f;
    float* slice = lds + wid * WAVE_F;

    int nch = 0;
    {   int rem = len - sbase;
        if (rem > 0) nch = (rem + CH - 1) >> 2;
        if (nch > NCHMAX) nch = NCHMAX;
    }

    if (nch > 0) {
        const float* pg0 = pred + ((size_t)b * SS + sbase) * (2 * KP);
        const float* xg0 = tgt + ((size_t)(b * 2 + 0) * SS + sbase) * KP;
        const float* yg0 = xg0 + (size_t)SS * KP;

        // chunk c plane bytes: 5 rows (padded to 2752B) or 4 rows (2192B) at the
        // very last chunk of the sequence (s0=508): tail lanes 44 or 9.
        auto tailL = [&](int c) {
            int s0 = sbase + 4 * c;
            return (SS - s0 >= 5) ? 44 : 9;
        };

        // prologue: stage chunk 0 -> buf0
        stage_chunk(pg0, xg0, yg0, slice, slice + PRED_F, slice + PRED_F + PLANE_F,
                    lane, tailL(0));

        for (int c = 0; c < nch; ++c) {
            float* bp = slice + (c & 1) * SLICE_F;
            if (c + 1 < nch) {
                // protect buf[(c+1)&1] against still-pending ds_reads of chunk c-1
                asm volatile("s_waitcnt lgkmcnt(0)" ::: "memory");
                float* np = slice + ((c + 1) & 1) * SLICE_F;
                const int o = 4 * (c + 1);
                stage_chunk(pg0 + (size_t)o * (2 * KP),
                            xg0 + (size_t)o * KP,
                            yg0 + (size_t)o * KP,
                            np, np + PRED_F, np + PRED_F + PLANE_F,
                            lane, tailL(c + 1));
                asm volatile("s_waitcnt vmcnt(11)" ::: "memory");  // chunk c done
            } else {
                asm volatile("s_waitcnt vmcnt(0)" ::: "memory");
            }
            __builtin_amdgcn_sched_barrier(0);
            compute_chunk(bp, sbase + 4 * c, len, lane, pose, bone);
        }
    }

    // wave reduce, then block reduce (single barrier at the end)
    for (int off = 32; off > 0; off >>= 1) {
        pose += __shfl_down(pose, off, 64);
        bone += __shfl_down(bone, off, 64);
    }
    if (lane == 0) wsum[wid] = make_float2(pose, bone);
    __syncthreads();
    if (t == 0) {
        float px = 0.f, bx = 0.f;
        #pragma unroll
        for (int i = 0; i < 4; ++i) { px += wsum[i].x; bx += wsum[i].y; }
        partials[blockIdx.x] = make_float2(px, bx);
    }
}

__global__ __launch_bounds__(256) void t2p_final(
    const float2* __restrict__ partials,
    const int* __restrict__ tlen,
    float* __restrict__ out)
{
    const int t = threadIdx.x;
    float ps = 0.f, bs = 0.f;
    #pragma unroll
    for (int i = 0; i < NBLK / 256; ++i) {
        float2 v = partials[t + i * 256];
        ps += v.x; bs += v.y;
    }
    float pc = 0.f, mc = 0.f;
    if (t < BB) {
        int len = tlen[t];
        pc = (float)(len - 1);   // sum(pose_mask)
        mc = (float)len;         // sum(mask)
    }
    for (int off = 32; off > 0; off >>= 1) {
        ps += __shfl_down(ps, off, 64);
        bs += __shfl_down(bs, off, 64);
        pc += __shfl_down(pc, off, 64);
        mc += __shfl_down(mc, off, 64);
    }
    __shared__ float4 wsum[4];
    if ((t & 63) == 0) wsum[t >> 6] = make_float4(ps, bs, pc, mc);
    __syncthreads();
    if (t == 0) {
        float4 a = wsum[0];
        for (int w = 1; w < 4; ++w) {
            a.x += wsum[w].x; a.y += wsum[w].y;
            a.z += wsum[w].z; a.w += wsum[w].w;
        }
        float pose_loss = a.x / (274.f * a.z);
        float bone_loss = (a.y * 0.5f) / ((136.f + 1e-8f) * a.w);
        out[0] = pose_loss + 0.1f * bone_loss;   // POSE_W=1, BONE_W=0.1
        out[1] = pose_loss;
        out[2] = bone_loss;
    }
}

extern "C" void kernel_launch(void* const* d_in, const int* in_sizes, int n_in,
                              void* d_out, int out_size, void* d_ws, size_t ws_size,
                              hipStream_t stream) {
    const float* pred = (const float*)d_in[0];   // [128,512,274] f32
    const float* tgt  = (const float*)d_in[1];   // [128,2,512,137] f32
    const int*   tlen = (const int*)d_in[2];     // [128] i32
    float* out = (float*)d_out;
    float2* partials = (float2*)d_ws;            // 1024 * 8 B = 8 KB

    t2p_main<<<NBLK, THREADS, 0, stream>>>(pred, tgt, tlen, partials);
    t2p_final<<<1, 256, 0, stream>>>(partials, tlen, out);
}

// Round 4
// 24.775 us; speedup vs baseline: 1.7292x; 1.1816x over previous
//
#include <hip/hip_runtime.h>

#define KP 137
#define SS 512
#define BB 128
#define THREADS 256
#define STRIP 8
#define NBLK 2048            // 2048 blocks x 4 waves = 8192 waves = 128 b x 64 strips

__global__ __launch_bounds__(THREADS) void t2p_main(
    const float* __restrict__ pred,      // [B,S,2K]
    const float* __restrict__ tgt,       // [B,2,S,K]
    const int*   __restrict__ tlen,      // [B]
    float2* __restrict__ partials)       // [NBLK]
{
    __shared__ float2 wsum[4];

    const int t    = threadIdx.x;
    const int lane = t & 63;
    const int wid  = t >> 6;
    const int w    = blockIdx.x * 4 + wid;   // 0..8191
    const int b    = w >> 6;                 // 64 strips per batch row
    const int s0   = (w & 63) * STRIP;
    const int len  = tlen[b];

    float pose = 0.f, bone = 0.f;

    if (s0 < len) {
        const int send = (len < s0 + STRIP) ? len : (s0 + STRIP);
        const float* txp = tgt + (size_t)(2 * b) * SS * KP;        // x plane
        const float* typ = txp + (size_t)SS * KP;                  // y plane
        const float2* pp = (const float2*)(pred + (size_t)b * SS * (2 * KP));

        const bool l2 = (lane <= 10);        // batch2 kps 126..136

        // prologue: target row s0 into rolling registers
        float tx0a, tx0b, tx0c, ty0a, ty0b, ty0c;
        {
            const float* r = txp + (size_t)s0 * KP;
            const float* q = typ + (size_t)s0 * KP;
            tx0a = r[lane]; tx0b = r[63 + lane]; tx0c = l2 ? r[126 + lane] : 0.f;
            ty0a = q[lane]; ty0b = q[63 + lane]; ty0c = l2 ? q[126 + lane] : 0.f;
        }

        for (int s = s0; s < send; ++s) {
            const float2* pr = pp + (size_t)s * KP;
            float2 pa = pr[lane];                                   // kp lane
            float2 pb = pr[63 + lane];                              // kp 63+lane
            float2 pc = l2 ? pr[126 + lane] : make_float2(0.f, 0.f);

            float tx1a = 0.f, tx1b = 0.f, tx1c = 0.f;
            float ty1a = 0.f, ty1b = 0.f, ty1c = 0.f;
            if (s + 1 < SS) {                                       // uniform branch
                const float* r = txp + (size_t)(s + 1) * KP;
                const float* q = typ + (size_t)(s + 1) * KP;
                tx1a = r[lane]; tx1b = r[63 + lane]; tx1c = l2 ? r[126 + lane] : 0.f;
                ty1a = q[lane]; ty1b = q[63 + lane]; ty1c = l2 ? q[126 + lane] : 0.f;
            }

            // pose: kp counted once: batch0 lanes 0..63 (kp 0..63),
            // batch1 lanes 1..63 (kp 64..126), batch2 lanes 1..10 (kp 127..136)
            if (s < len - 1) {
                float acc = fabsf(pa.x - tx1a) + fabsf(pa.y - ty1a);
                if (lane >= 1)       acc += fabsf(pb.x - tx1b) + fabsf(pb.y - ty1b);
                if (lane >= 1 && l2) acc += fabsf(pc.x - tx1c) + fabsf(pc.y - ty1c);
                pose += acc;
            }

            // e = pred - target (same row)
            float exa = pa.x - tx0a, eya = pa.y - ty0a;
            float exb = pb.x - tx0b, eyb = pb.y - ty0b;
            float exc = pc.x - tx0c, eyc = pc.y - ty0c;

            // bone pairs, all intra-batch: batch0 pairs k=0..62 (lane<63),
            // batch1 pairs k=63..125 (lane<63), batch2 pairs k=126..135 (lane<10)
            float nxa = __shfl_down(exa, 1, 64), nya = __shfl_down(eya, 1, 64);
            float nxb = __shfl_down(exb, 1, 64), nyb = __shfl_down(eyb, 1, 64);
            float nxc = __shfl_down(exc, 1, 64), nyc = __shfl_down(eyc, 1, 64);
            float acc = 0.f;
            if (lane < 63) {
                float dx = nxa - exa, dy = nya - eya;
                acc += dx * dx + dy * dy;
                float ex = nxb - exb, ey = nyb - eyb;
                acc += ex * ex + ey * ey;
            }
            if (lane < 10) {
                float dx = nxc - exc, dy = nyc - eyc;
                acc += dx * dx + dy * dy;
            }
            bone += acc;

            // roll: target row s+1 becomes row s of next iteration
            tx0a = tx1a; tx0b = tx1b; tx0c = tx1c;
            ty0a = ty1a; ty0b = ty1b; ty0c = ty1c;
        }
    }

    // wave reduce, then block reduce (single barrier at the very end)
    for (int off = 32; off > 0; off >>= 1) {
        pose += __shfl_down(pose, off, 64);
        bone += __shfl_down(bone, off, 64);
    }
    if (lane == 0) wsum[wid] = make_float2(pose, bone);
    __syncthreads();
    if (t == 0) {
        float px = 0.f, bx = 0.f;
        #pragma unroll
        for (int i = 0; i < 4; ++i) { px += wsum[i].x; bx += wsum[i].y; }
        partials[blockIdx.x] = make_float2(px, bx);
    }
}

__global__ __launch_bounds__(256) void t2p_final(
    const float2* __restrict__ partials,
    const int* __restrict__ tlen,
    float* __restrict__ out)
{
    const int t = threadIdx.x;
    float ps = 0.f, bs = 0.f;
    #pragma unroll
    for (int i = 0; i < NBLK / 256; ++i) {
        float2 v = partials[t + i * 256];
        ps += v.x; bs += v.y;
    }
    float pc = 0.f, mc = 0.f;
    if (t < BB) {
        int len = tlen[t];
        pc = (float)(len - 1);   // sum(pose_mask)
        mc = (float)len;         // sum(mask)
    }
    for (int off = 32; off > 0; off >>= 1) {
        ps += __shfl_down(ps, off, 64);
        bs += __shfl_down(bs, off, 64);
        pc += __shfl_down(pc, off, 64);
        mc += __shfl_down(mc, off, 64);
    }
    __shared__ float4 wsum[4];
    if ((t & 63) == 0) wsum[t >> 6] = make_float4(ps, bs, pc, mc);
    __syncthreads();
    if (t == 0) {
        float4 a = wsum[0];
        for (int w = 1; w < 4; ++w) {
            a.x += wsum[w].x; a.y += wsum[w].y;
            a.z += wsum[w].z; a.w += wsum[w].w;
        }
        float pose_loss = a.x / (274.f * a.z);
        float bone_loss = (a.y * 0.5f) / ((136.f + 1e-8f) * a.w);
        out[0] = pose_loss + 0.1f * bone_loss;   // POSE_W=1, BONE_W=0.1
        out[1] = pose_loss;
        out[2] = bone_loss;
    }
}

extern "C" void kernel_launch(void* const* d_in, const int* in_sizes, int n_in,
                              void* d_out, int out_size, void* d_ws, size_t ws_size,
                              hipStream_t stream) {
    const float* pred = (const float*)d_in[0];   // [128,512,274] f32
    const float* tgt  = (const float*)d_in[1];   // [128,2,512,137] f32
    const int*   tlen = (const int*)d_in[2];     // [128] i32
    float* out = (float*)d_out;
    float2* partials = (float2*)d_ws;            // 2048 * 8 B = 16 KB

    t2p_main<<<NBLK, THREADS, 0, stream>>>(pred, tgt, tlen, partials);
    t2p_final<<<1, 256, 0, stream>>>(partials, tlen, out);
}